// Round 8
// baseline (458.783 us; speedup 1.0000x reference)
//
#include <hip/hip_runtime.h>

// GAT on fully-connected graph, N=4096, F=D=64, H=4, OUT=2.
// Whole model in ONE kernel (regular launch, 256 blocks = 1/CU, all co-resident)
// with a software grid barrier (counter+flag, device-scope atomics) replacing
// the broken hipLaunchCooperativeKernel path. e[t,s,h]=lrelu(dst_t+src_s)
// factors per branch around -dst: sorted-source suffix/prefix weighted tables
// + rank search per target.

#define N 4096
#define D 64
#define H 4
#define HD 256
#define TS 66
#define NBLK 256

struct Params {
  const float *x, *Wenc, *benc;
  const float *W1, *as1, *ad1, *b1;
  const float *W2, *as2, *ad2, *b2;
  const float *Wact, *bact, *Wcri, *bcri;
  float *out;
  float *h2, *ssrc1, *sdst1, *ssrc2, *sdst2, *srtv;
  int *srti, *rpart;
  float *wA, *wB, *TA, *TB, *SA, *PB;
  int *bar;   // 2 ints per sync point, zeroed before launch
};

// ---- software grid barrier: arrive-count + release flag ----
__device__ __forceinline__ void gsync(int* bar, int idx) {
  __syncthreads();
  if (threadIdx.x == 0) {
    __threadfence();                                   // release our writes
    int prev = __hip_atomic_fetch_add(&bar[2 * idx], 1,
                 __ATOMIC_ACQ_REL, __HIP_MEMORY_SCOPE_AGENT);
    if (prev == NBLK - 1) {
      __hip_atomic_store(&bar[2 * idx + 1], 1,
                 __ATOMIC_RELEASE, __HIP_MEMORY_SCOPE_AGENT);
    } else {
      while (__hip_atomic_load(&bar[2 * idx + 1],
                 __ATOMIC_ACQUIRE, __HIP_MEMORY_SCOPE_AGENT) == 0) {
        __builtin_amdgcn_s_sleep(1);
      }
    }
    __threadfence();                                   // acquire others' writes
  }
  __syncthreads();
}

__device__ __forceinline__ void fma4(float4& a, float s, const float4& b) {
  a.x = fmaf(s, b.x, a.x); a.y = fmaf(s, b.y, a.y);
  a.z = fmaf(s, b.z, a.z); a.w = fmaf(s, b.w, a.w);
}

// ---- proj: 8 rows from LDS xs, W from global; writes h2, ssrc, sdst ----
__device__ __forceinline__ void proj_dev(const float (*xs)[64], int r0,
    const float* __restrict__ W, const float* __restrict__ asrc,
    const float* __restrict__ adst, float* __restrict__ h2,
    float* __restrict__ ssrc, float* __restrict__ sdst) {
  int tid = threadIdx.x;
  int lane6 = tid & 63;
  int c0 = lane6 * 4;
  int hh = lane6 >> 4;
  int rbase = (tid >> 6) * 2;
  float4 acc0 = make_float4(0.f, 0.f, 0.f, 0.f);
  float4 acc1 = make_float4(0.f, 0.f, 0.f, 0.f);
#pragma unroll
  for (int kq = 0; kq < 16; ++kq) {
    const float* Wk = W + kq * 4 * 256 + c0;
    float4 w0 = *(const float4*)(Wk);
    float4 w1 = *(const float4*)(Wk + 256);
    float4 w2 = *(const float4*)(Wk + 512);
    float4 w3 = *(const float4*)(Wk + 768);
    float4 x0 = *(const float4*)(&xs[rbase][kq * 4]);
    float4 x1 = *(const float4*)(&xs[rbase + 1][kq * 4]);
    fma4(acc0, x0.x, w0); fma4(acc0, x0.y, w1); fma4(acc0, x0.z, w2); fma4(acc0, x0.w, w3);
    fma4(acc1, x1.x, w0); fma4(acc1, x1.y, w1); fma4(acc1, x1.z, w2); fma4(acc1, x1.w, w3);
  }
  float4 av = *(const float4*)(asrc + c0);
  float4 bv = *(const float4*)(adst + c0);
#pragma unroll
  for (int r = 0; r < 2; ++r) {
    float4 a = (r == 0) ? acc0 : acc1;
    int row = r0 + rbase + r;
    *(float4*)(h2 + row * 256 + c0) = a;
    float ps = a.x * av.x + a.y * av.y + a.z * av.z + a.w * av.w;
    float pd = a.x * bv.x + a.y * bv.y + a.z * bv.z + a.w * bv.w;
#pragma unroll
    for (int off = 8; off > 0; off >>= 1) {
      ps += __shfl_down(ps, off);
      pd += __shfl_down(pd, off);
    }
    if ((lane6 & 15) == 0) {
      ssrc[hh * N + row] = ps;
      sdst[hh * N + row] = pd;
    }
  }
}

// ---- rank stage 1: 1024 tasks = h(4) x ig(16) x c(16), 4 per block ----
__device__ __forceinline__ void rank1_dev(int b, int tid,
    const float* __restrict__ ssrc, int* __restrict__ rpart, float* vs) {
  for (int task = b; task < 1024; task += NBLK) {
    int h = task >> 8, ig = (task >> 4) & 15, c = task & 15;
    __syncthreads();
    vs[tid] = ssrc[h * N + c * 256 + tid];
    __syncthreads();
    int i = ig * 256 + tid;
    float vi = ssrc[h * N + i];
    const float4* vs4 = (const float4*)vs;
    int jbase = c * 256;
    int rank = 0;
#pragma unroll 4
    for (int j4 = 0; j4 < 64; ++j4) {
      float4 q = vs4[j4];
      int jb = jbase + (j4 << 2);
      rank += (q.x < vi || (q.x == vi && jb < i));
      rank += (q.y < vi || (q.y == vi && jb + 1 < i));
      rank += (q.z < vi || (q.z == vi && jb + 2 < i));
      rank += (q.w < vi || (q.w == vi && jb + 3 < i));
    }
    rpart[(c * H + h) * N + i] = rank;
  }
}

// ---- rank stage 2: reduce 16 partials + scatter (64 active blocks) ----
__device__ __forceinline__ void rank2_dev(int b, int tid,
    const float* __restrict__ ssrc, const int* __restrict__ rpart,
    float* __restrict__ srtv, int* __restrict__ srti) {
  if (b < 64) {
    int h = b >> 4, ig = b & 15;
    int i = ig * 256 + tid;
    int rank = 0;
#pragma unroll
    for (int c = 0; c < 16; ++c) rank += rpart[(c * H + h) * N + i];
    srtv[h * N + rank] = ssrc[h * N + i];
    srti[h * N + rank] = i;
  }
}

// ---- S1: per-chunk totals + weights (all 256 blocks) ----
__device__ __forceinline__ void s1_dev(int b, int tid,
    const float* __restrict__ h2, const int* __restrict__ srti,
    const float* __restrict__ srtv, float* __restrict__ wA, float* __restrict__ wB,
    float* __restrict__ TA, float* __restrict__ TB,
    int* pj, float* wa, float* wb) {
  int h = b >> 6, c = b & 63, col = tid;
  int j0 = c * 64;
  float m1 = srtv[h * N + N - 1];
  if (col < 64) {
    int j = j0 + col;
    pj[col] = srti[h * N + j];
    float sv = srtv[h * N + j];
    float a = expf(sv - m1);
    float bb = expf(0.2f * (sv - m1));
    wa[col] = a; wb[col] = bb;
    wA[h * N + j] = a; wB[h * N + j] = bb;
  }
  __syncthreads();
  if (col < 65) {
    float accA = 0.f, accB = 0.f;
#pragma unroll 8
    for (int j = 0; j < 64; ++j) {
      float val = (col < 64) ? h2[pj[j] * HD + h * 64 + col] : 1.0f;
      accA = fmaf(wa[j], val, accA);
      accB = fmaf(wb[j], val, accB);
    }
    TA[(h * 64 + c) * TS + col] = accA;
    TB[(h * 64 + c) * TS + col] = accB;
  }
}

// ---- S3: offsets + full suffix/prefix tables (all 256 blocks) ----
__device__ __forceinline__ void s3_dev(int b, int tid,
    const float* __restrict__ h2, const int* __restrict__ srti,
    const float* __restrict__ wA, const float* __restrict__ wB,
    const float* __restrict__ TA, const float* __restrict__ TB,
    float* __restrict__ SA, float* __restrict__ PB,
    int* pj, float* wa, float* wb) {
  int h = b >> 6, c = b & 63, col = tid;
  int j0 = c * 64;
  __syncthreads();
  if (col < 64) {
    pj[col] = srti[h * N + j0 + col];
    wa[col] = wA[h * N + j0 + col];
    wb[col] = wB[h * N + j0 + col];
  }
  __syncthreads();
  if (col < 65) {
    float offA = 0.f, offB = 0.f;
    for (int cc = c + 1; cc < 64; ++cc) offA += TA[(h * 64 + cc) * TS + col];
    for (int cc = 0; cc < c; ++cc)      offB += TB[(h * 64 + cc) * TS + col];
    float v[64];
#pragma unroll
    for (int j = 0; j < 64; ++j)
      v[j] = (col < 64) ? h2[pj[j] * HD + h * 64 + col] : 1.0f;
    float acc = offA;
#pragma unroll
    for (int j = 63; j >= 0; --j) {
      acc = fmaf(wa[j], v[j], acc);
      SA[(size_t)(h * (N + 1) + j0 + j) * TS + col] = acc;
    }
    acc = offB;
#pragma unroll
    for (int j = 0; j < 64; ++j) {
      acc = fmaf(wb[j], v[j], acc);
      PB[(size_t)(h * (N + 1) + j0 + j + 1) * TS + col] = acc;
    }
    if (c == 63) SA[(size_t)(h * (N + 1) + N) * TS + col] = 0.f;
    if (c == 0)  PB[(size_t)(h * (N + 1) + 0) * TS + col] = 0.f;
  }
}

// ---- target: 8 rows starting at t0; MODE0 -> xs LDS; MODE1 -> heads+out ----
template <int MODE>
__device__ __forceinline__ void target_dev(int t0, int tid,
    const float* __restrict__ sdst, const float* __restrict__ srtv,
    const float* __restrict__ SA, const float* __restrict__ PB,
    const float* __restrict__ bias, float (*xsout)[64], const float (*bnd)[64],
    const float* __restrict__ Wact, const float* __restrict__ bact,
    const float* __restrict__ Wcri, const float* __restrict__ bcri,
    float* __restrict__ out) {
  int lane = tid & 63;
#pragma unroll
  for (int task = 0; task < 2; ++task) {
    int r = task * 4 + (tid >> 6);
    int t = t0 + r;
    float acc = 0.f;
#pragma unroll
    for (int h = 0; h < H; ++h) {
      const float* sv = srtv + h * N;
      float dst = sdst[h * N + t];
      float thr = -dst;
      float m1 = sv[N - 1];
      unsigned long long b1m = __ballot(bnd[h][lane] <= thr);
      int c1 = __popcll(b1m);
      int seg = c1 > 0 ? c1 - 1 : 0;
      unsigned long long b2m = __ballot(sv[seg * 64 + lane] <= thr);
      int k = seg * 64 + __popcll(b2m);
      float u = dst + m1;
      float g = fmaxf(u, 0.2f * u);
      float wAt = expf(u - g);
      float wBt = expf(0.2f * u - g);
      const float* sa = SA + (size_t)(h * (N + 1) + k) * TS;
      const float* pb = PB + (size_t)(h * (N + 1) + k) * TS;
      float num = wAt * sa[lane] + wBt * pb[lane];
      float den = wAt * sa[64] + wBt * pb[64];
      acc += num / den;
    }
    float hv = fmaxf(acc * 0.25f + bias[lane], 0.f);
    if constexpr (MODE == 0) {
      xsout[r][lane] = hv;
    } else {
      float p0 = hv * Wact[lane * 2 + 0];
      float p1 = hv * Wact[lane * 2 + 1];
      float p2 = hv * Wcri[lane];
#pragma unroll
      for (int off = 32; off > 0; off >>= 1) {
        p0 += __shfl_down(p0, off);
        p1 += __shfl_down(p1, off);
        p2 += __shfl_down(p2, off);
      }
      if (lane == 0) {
        float l0 = fminf(fmaxf(p0 + bact[0], -5.f), 5.f);
        float l1 = fminf(fmaxf(p1 + bact[1], -5.f), 5.f);
        out[t * 2 + 0] = l0;
        out[t * 2 + 1] = fabsf(l1);
        out[2 * N + t] = p2 + bcri[0];
      }
    }
  }
}

__global__ __launch_bounds__(256, 1) void k_fused(Params P) {
  __shared__ float xs[8][64];
  __shared__ __align__(16) float vs[256];
  __shared__ int pj[64];
  __shared__ float wa[64], wb[64];
  __shared__ float bnd[4][64];
  const int b = blockIdx.x;
  const int tid = threadIdx.x;
  int* bar = P.bar;

  // ---- P0: encoder + proj1, 16 rows/block in two 8-row halves ----
#pragma unroll
  for (int half = 0; half < 2; ++half) {
    int r0 = (b * 2 + half) * 8;
    int row = tid >> 5, c = (tid & 31) * 2;
    const float* xr = P.x + (r0 + row) * 64;
    float a0 = P.benc[c], a1 = P.benc[c + 1];
#pragma unroll
    for (int k = 0; k < 64; ++k) {
      float xv = xr[k];
      float2 w = *(const float2*)(P.Wenc + k * 64 + c);
      a0 = fmaf(xv, w.x, a0);
      a1 = fmaf(xv, w.y, a1);
    }
    __syncthreads();   // prev half's proj readers done with xs
    xs[row][c] = fmaxf(a0, 0.f);
    xs[row][c + 1] = fmaxf(a1, 0.f);
    __syncthreads();
    proj_dev(xs, r0, P.W1, P.as1, P.ad1, P.h2, P.ssrc1, P.sdst1);
  }
  gsync(bar, 0);
  rank1_dev(b, tid, P.ssrc1, P.rpart, vs);
  gsync(bar, 1);
  rank2_dev(b, tid, P.ssrc1, P.rpart, P.srtv, P.srti);
  gsync(bar, 2);
  s1_dev(b, tid, P.h2, P.srti, P.srtv, P.wA, P.wB, P.TA, P.TB, pj, wa, wb);
  gsync(bar, 3);
  s3_dev(b, tid, P.h2, P.srti, P.wA, P.wB, P.TA, P.TB, P.SA, P.PB, pj, wa, wb);
  gsync(bar, 4);
  // ---- P5: target1 -> xs (LDS) -> proj2 in-block, two halves ----
  {
    int hh = tid >> 6, l = tid & 63;
    bnd[hh][l] = P.srtv[hh * N + l * 64];
    __syncthreads();
#pragma unroll
    for (int half = 0; half < 2; ++half) {
      int r0 = (b * 2 + half) * 8;
      target_dev<0>(r0, tid, P.sdst1, P.srtv, P.SA, P.PB, P.b1, xs, bnd,
                    nullptr, nullptr, nullptr, nullptr, nullptr);
      __syncthreads();
      proj_dev(xs, r0, P.W2, P.as2, P.ad2, P.h2, P.ssrc2, P.sdst2);
      __syncthreads();   // proj readers done before next half rewrites xs
    }
  }
  gsync(bar, 5);
  rank1_dev(b, tid, P.ssrc2, P.rpart, vs);
  gsync(bar, 6);
  rank2_dev(b, tid, P.ssrc2, P.rpart, P.srtv, P.srti);
  gsync(bar, 7);
  s1_dev(b, tid, P.h2, P.srti, P.srtv, P.wA, P.wB, P.TA, P.TB, pj, wa, wb);
  gsync(bar, 8);
  s3_dev(b, tid, P.h2, P.srti, P.wA, P.wB, P.TA, P.TB, P.SA, P.PB, pj, wa, wb);
  gsync(bar, 9);
  // ---- P10: target2 + heads, two halves ----
  {
    __syncthreads();
    int hh = tid >> 6, l = tid & 63;
    bnd[hh][l] = P.srtv[hh * N + l * 64];
    __syncthreads();
#pragma unroll
    for (int half = 0; half < 2; ++half) {
      target_dev<1>((b * 2 + half) * 8, tid, P.sdst2, P.srtv, P.SA, P.PB, P.b2,
                    nullptr, bnd, P.Wact, P.bact, P.Wcri, P.bcri, P.out);
    }
  }
}

extern "C" void kernel_launch(void* const* d_in, const int* in_sizes, int n_in,
                              void* d_out, int out_size, void* d_ws, size_t ws_size,
                              hipStream_t stream) {
    (void)in_sizes; (void)n_in; (void)out_size; (void)ws_size;
    Params P;
    P.x     = (const float*)d_in[0];
    P.Wenc  = (const float*)d_in[1];
    P.benc  = (const float*)d_in[2];
    P.W1    = (const float*)d_in[3];
    P.as1   = (const float*)d_in[4];
    P.ad1   = (const float*)d_in[5];
    P.b1    = (const float*)d_in[6];
    P.W2    = (const float*)d_in[7];
    P.as2   = (const float*)d_in[8];
    P.ad2   = (const float*)d_in[9];
    P.b2    = (const float*)d_in[10];
    P.Wact  = (const float*)d_in[11];
    P.bact  = (const float*)d_in[12];
    P.Wcri  = (const float*)d_in[13];
    P.bcri  = (const float*)d_in[14];
    P.out   = (float*)d_out;

    float* p = (float*)d_ws;
    P.h2    = p; p += N * HD;
    P.ssrc1 = p; p += H * N;
    P.sdst1 = p; p += H * N;
    P.ssrc2 = p; p += H * N;
    P.sdst2 = p; p += H * N;
    P.srtv  = p; p += H * N;
    P.srti  = (int*)p; p += H * N;
    P.wA    = p; p += H * N;
    P.wB    = p; p += H * N;
    P.TA    = p; p += H * 64 * TS;
    P.TB    = p; p += H * 64 * TS;
    P.SA    = p; p += (size_t)H * (N + 1) * TS;
    P.PB    = p; p += (size_t)H * (N + 1) * TS;
    P.rpart = (int*)p; p += 16 * H * N;
    P.bar   = (int*)p; p += 32;

    hipMemsetAsync(P.bar, 0, 32 * sizeof(int), stream);
    k_fused<<<NBLK, 256, 0, stream>>>(P);
}

// Round 9
// 235.262 us; speedup vs baseline: 1.9501x; 1.9501x over previous
//
#include <hip/hip_runtime.h>

// GAT on fully-connected graph, N=4096, F=D=64, H=4, OUT=2.
// Split-kernel structure (each phase at its ideal grid) but only 7 dispatches:
//  encproj -> rank(fused last-block-reduce) -> scan(s1+s3, spin) ->
//  targetproj -> rank -> scan -> target2+heads.
// e[t,s,h]=lrelu(dst_t+src_s) factors per branch around -dst: sorted-source
// suffix/prefix weighted tables + rank search per target.

#define N 4096
#define D 64
#define H 4
#define HD 256
#define TS 66

__device__ __forceinline__ void fma4(float4& a, float s, const float4& b) {
  a.x = fmaf(s, b.x, a.x); a.y = fmaf(s, b.y, a.y);
  a.z = fmaf(s, b.z, a.z); a.w = fmaf(s, b.w, a.w);
}

// ---- proj: 8 rows from LDS xs, W from global; writes h2, ssrc, sdst ----
__device__ __forceinline__ void proj_dev(const float (*xs)[64], int r0,
    const float* __restrict__ W, const float* __restrict__ asrc,
    const float* __restrict__ adst, float* __restrict__ h2,
    float* __restrict__ ssrc, float* __restrict__ sdst) {
  int tid = threadIdx.x;
  int lane6 = tid & 63;
  int c0 = lane6 * 4;
  int hh = lane6 >> 4;
  int rbase = (tid >> 6) * 2;
  float4 acc0 = make_float4(0.f, 0.f, 0.f, 0.f);
  float4 acc1 = make_float4(0.f, 0.f, 0.f, 0.f);
#pragma unroll
  for (int kq = 0; kq < 16; ++kq) {
    const float* Wk = W + kq * 4 * 256 + c0;
    float4 w0 = *(const float4*)(Wk);
    float4 w1 = *(const float4*)(Wk + 256);
    float4 w2 = *(const float4*)(Wk + 512);
    float4 w3 = *(const float4*)(Wk + 768);
    float4 x0 = *(const float4*)(&xs[rbase][kq * 4]);
    float4 x1 = *(const float4*)(&xs[rbase + 1][kq * 4]);
    fma4(acc0, x0.x, w0); fma4(acc0, x0.y, w1); fma4(acc0, x0.z, w2); fma4(acc0, x0.w, w3);
    fma4(acc1, x1.x, w0); fma4(acc1, x1.y, w1); fma4(acc1, x1.z, w2); fma4(acc1, x1.w, w3);
  }
  float4 av = *(const float4*)(asrc + c0);
  float4 bv = *(const float4*)(adst + c0);
#pragma unroll
  for (int r = 0; r < 2; ++r) {
    float4 a = (r == 0) ? acc0 : acc1;
    int row = r0 + rbase + r;
    *(float4*)(h2 + row * 256 + c0) = a;
    float ps = a.x * av.x + a.y * av.y + a.z * av.z + a.w * av.w;
    float pd = a.x * bv.x + a.y * bv.y + a.z * bv.z + a.w * bv.w;
#pragma unroll
    for (int off = 8; off > 0; off >>= 1) {
      ps += __shfl_down(ps, off);
      pd += __shfl_down(pd, off);
    }
    if ((lane6 & 15) == 0) {
      ssrc[hh * N + row] = ps;
      sdst[hh * N + row] = pd;
    }
  }
}

// ---- layer1: encoder fused with proj ----
__global__ __launch_bounds__(256) void k_encproj(const float* __restrict__ x,
    const float* __restrict__ Wenc, const float* __restrict__ benc,
    const float* __restrict__ W, const float* __restrict__ asrc,
    const float* __restrict__ adst, float* __restrict__ h2,
    float* __restrict__ ssrc, float* __restrict__ sdst) {
  __shared__ float xs[8][64];
  int tid = threadIdx.x;
  int r0 = blockIdx.x * 8;
  {
    int row = tid >> 5, c = (tid & 31) * 2;
    const float* xr = x + (r0 + row) * 64;
    float a0 = benc[c], a1 = benc[c + 1];
#pragma unroll
    for (int k = 0; k < 64; ++k) {
      float xv = xr[k];
      float2 w = *(const float2*)(Wenc + k * 64 + c);
      a0 = fmaf(xv, w.x, a0);
      a1 = fmaf(xv, w.y, a1);
    }
    xs[row][c] = fmaxf(a0, 0.f);
    xs[row][c + 1] = fmaxf(a1, 0.f);
  }
  __syncthreads();
  proj_dev(xs, r0, W, asrc, adst, h2, ssrc, sdst);
}

// ---- rank fused: partial counts; LAST block per (h,ig) reduces + scatters ----
// grid (64, 16): x = h*16+ig, y = c. No spinning -> no co-residency needed.
__global__ __launch_bounds__(256) void k_rank_f(const float* __restrict__ ssrc,
    int* __restrict__ rpart, int* __restrict__ cnt,
    float* __restrict__ srtv, int* __restrict__ srti) {
  __shared__ __align__(16) float vs[256];
  __shared__ int lastflag;
  int h = blockIdx.x >> 4, ig = blockIdx.x & 15, c = blockIdx.y;
  int tid = threadIdx.x;
  vs[tid] = ssrc[h * N + c * 256 + tid];
  __syncthreads();
  int i = ig * 256 + tid;
  float vi = ssrc[h * N + i];
  int jbase = c * 256;
  int rank = 0;
  const float4* vs4 = (const float4*)vs;
#pragma unroll 4
  for (int j4 = 0; j4 < 64; ++j4) {
    float4 q = vs4[j4];
    int jb = jbase + (j4 << 2);
    rank += (q.x < vi || (q.x == vi && jb < i));
    rank += (q.y < vi || (q.y == vi && jb + 1 < i));
    rank += (q.z < vi || (q.z == vi && jb + 2 < i));
    rank += (q.w < vi || (q.w == vi && jb + 3 < i));
  }
  rpart[(c * H + h) * N + i] = rank;
  if (tid == 0) {
    __threadfence();   // make rpart visible before counting in
    int prev = __hip_atomic_fetch_add(&cnt[h * 16 + ig], 1,
                 __ATOMIC_ACQ_REL, __HIP_MEMORY_SCOPE_AGENT);
    lastflag = (prev == 15);
  }
  __syncthreads();
  if (lastflag) {
    __threadfence();   // acquire peers' rpart
    int rk = 0;
#pragma unroll
    for (int cc = 0; cc < 16; ++cc) rk += rpart[(cc * H + h) * N + i];
    srtv[h * N + rk] = vi;
    srti[h * N + rk] = i;
  }
}

// ---- scan: s1 totals + publish, spin for head complete, s3 tables ----
// grid 256 (h*64+c), block 128. All blocks co-resident (256 blocks of 2 waves).
__global__ __launch_bounds__(128) void k_scan(const float* __restrict__ h2,
    const int* __restrict__ srti, const float* __restrict__ srtv,
    float* __restrict__ TA, float* __restrict__ TB, int* __restrict__ done,
    float* __restrict__ SA, float* __restrict__ PB) {
  __shared__ int pj[64];
  __shared__ float wa[64], wb[64];
  int h = blockIdx.x >> 6, c = blockIdx.x & 63, col = threadIdx.x;
  int j0 = c * 64;
  float m1 = srtv[h * N + N - 1];
  if (col < 64) {
    int j = j0 + col;
    pj[col] = srti[h * N + j];
    float sv = srtv[h * N + j];
    wa[col] = expf(sv - m1);
    wb[col] = expf(0.2f * (sv - m1));
  }
  __syncthreads();
  float v[64];
  if (col < 65) {
    float tA = 0.f, tB = 0.f;
#pragma unroll
    for (int j = 0; j < 64; ++j) {
      v[j] = (col < 64) ? h2[pj[j] * HD + h * 64 + col] : 1.0f;
      tA = fmaf(wa[j], v[j], tA);
      tB = fmaf(wb[j], v[j], tB);
    }
    TA[(h * 64 + c) * TS + col] = tA;
    TB[(h * 64 + c) * TS + col] = tB;
  }
  __syncthreads();
  if (col == 0) {
    __threadfence();
    __hip_atomic_fetch_add(&done[h], 1, __ATOMIC_ACQ_REL, __HIP_MEMORY_SCOPE_AGENT);
    while (__hip_atomic_load(&done[h], __ATOMIC_ACQUIRE, __HIP_MEMORY_SCOPE_AGENT) < 64)
      __builtin_amdgcn_s_sleep(2);
  }
  __syncthreads();
  __threadfence();   // acquire all chunks' totals
  if (col < 65) {
    float offA = 0.f, offB = 0.f;
    for (int cc = c + 1; cc < 64; ++cc) offA += TA[(h * 64 + cc) * TS + col];
    for (int cc = 0; cc < c; ++cc)      offB += TB[(h * 64 + cc) * TS + col];
    float acc = offA;
#pragma unroll
    for (int j = 63; j >= 0; --j) {  // SA[i] = sum_{j>=i} wA_j v_j
      acc = fmaf(wa[j], v[j], acc);
      SA[(size_t)(h * (N + 1) + j0 + j) * TS + col] = acc;
    }
    acc = offB;
#pragma unroll
    for (int j = 0; j < 64; ++j) {   // PB[i] = sum_{j<i} wB_j v_j
      acc = fmaf(wb[j], v[j], acc);
      PB[(size_t)(h * (N + 1) + j0 + j + 1) * TS + col] = acc;
    }
    if (c == 63) SA[(size_t)(h * (N + 1) + N) * TS + col] = 0.f;
    if (c == 0)  PB[(size_t)(h * (N + 1) + 0) * TS + col] = 0.f;
  }
}

// ---- target core: 4 rows (t0 + tid>>6 + 4*task) ----
template <int MODE>
__device__ __forceinline__ void target_dev(int t0, int tid,
    const float* __restrict__ sdst, const float* __restrict__ srtv,
    const float* __restrict__ SA, const float* __restrict__ PB,
    const float* __restrict__ bias, float (*xsout)[64], const float (*bnd)[64],
    const float* __restrict__ Wact, const float* __restrict__ bact,
    const float* __restrict__ Wcri, const float* __restrict__ bcri,
    float* __restrict__ out, int ntask) {
  int lane = tid & 63;
  for (int task = 0; task < ntask; ++task) {
    int r = task * 4 + (tid >> 6);
    int t = t0 + r;
    float acc = 0.f;
#pragma unroll
    for (int h = 0; h < H; ++h) {
      const float* sv = srtv + h * N;
      float dst = sdst[h * N + t];
      float thr = -dst;
      float m1 = sv[N - 1];
      unsigned long long b1m = __ballot(bnd[h][lane] <= thr);
      int c1 = __popcll(b1m);
      int seg = c1 > 0 ? c1 - 1 : 0;
      unsigned long long b2m = __ballot(sv[seg * 64 + lane] <= thr);
      int k = seg * 64 + __popcll(b2m);
      float u = dst + m1;
      float g = fmaxf(u, 0.2f * u);
      float wAt = expf(u - g);
      float wBt = expf(0.2f * u - g);
      const float* sa = SA + (size_t)(h * (N + 1) + k) * TS;
      const float* pb = PB + (size_t)(h * (N + 1) + k) * TS;
      float num = wAt * sa[lane] + wBt * pb[lane];
      float den = wAt * sa[64] + wBt * pb[64];
      acc += num / den;
    }
    float hv = fmaxf(acc * 0.25f + bias[lane], 0.f);
    if constexpr (MODE == 0) {
      xsout[r][lane] = hv;
    } else {
      float p0 = hv * Wact[lane * 2 + 0];
      float p1 = hv * Wact[lane * 2 + 1];
      float p2 = hv * Wcri[lane];
#pragma unroll
      for (int off = 32; off > 0; off >>= 1) {
        p0 += __shfl_down(p0, off);
        p1 += __shfl_down(p1, off);
        p2 += __shfl_down(p2, off);
      }
      if (lane == 0) {
        float l0 = fminf(fmaxf(p0 + bact[0], -5.f), 5.f);
        float l1 = fminf(fmaxf(p1 + bact[1], -5.f), 5.f);
        out[t * 2 + 0] = l0;
        out[t * 2 + 1] = fabsf(l1);
        out[2 * N + t] = p2 + bcri[0];
      }
    }
  }
}

// ---- target1 (8 rows -> LDS) fused with proj2 ----
__global__ __launch_bounds__(256) void k_targetproj(
    const float* __restrict__ sdst, const float* __restrict__ srtv,
    const float* __restrict__ SA, const float* __restrict__ PB,
    const float* __restrict__ bias,
    const float* __restrict__ W, const float* __restrict__ asrc,
    const float* __restrict__ adst, float* __restrict__ h2,
    float* __restrict__ ssrc2, float* __restrict__ sdst2) {
  __shared__ float xs[8][64];
  __shared__ float bnd[4][64];
  int tid = threadIdx.x;
  int r0 = blockIdx.x * 8;
  { int hh = tid >> 6, l = tid & 63; bnd[hh][l] = srtv[hh * N + l * 64]; }
  __syncthreads();
  target_dev<0>(r0, tid, sdst, srtv, SA, PB, bias, xs, bnd,
                nullptr, nullptr, nullptr, nullptr, nullptr, 2);
  __syncthreads();
  proj_dev(xs, r0, W, asrc, adst, h2, ssrc2, sdst2);
}

// ---- target2 + heads ----
__global__ __launch_bounds__(256) void k_target2(
    const float* __restrict__ sdst, const float* __restrict__ srtv,
    const float* __restrict__ SA, const float* __restrict__ PB,
    const float* __restrict__ bias,
    const float* __restrict__ Wact, const float* __restrict__ bact,
    const float* __restrict__ Wcri, const float* __restrict__ bcri,
    float* __restrict__ out) {
  __shared__ float bnd[4][64];
  int tid = threadIdx.x;
  { int hh = tid >> 6, l = tid & 63; bnd[hh][l] = srtv[hh * N + l * 64]; }
  __syncthreads();
  target_dev<1>(blockIdx.x * 4, tid, sdst, srtv, SA, PB, bias, nullptr, bnd,
                Wact, bact, Wcri, bcri, out, 1);
}

extern "C" void kernel_launch(void* const* d_in, const int* in_sizes, int n_in,
                              void* d_out, int out_size, void* d_ws, size_t ws_size,
                              hipStream_t stream) {
    (void)in_sizes; (void)n_in; (void)out_size; (void)ws_size;
    const float* x     = (const float*)d_in[0];
    const float* W_enc = (const float*)d_in[1];
    const float* b_enc = (const float*)d_in[2];
    const float* W1    = (const float*)d_in[3];
    const float* as1   = (const float*)d_in[4];
    const float* ad1   = (const float*)d_in[5];
    const float* b1    = (const float*)d_in[6];
    const float* W2    = (const float*)d_in[7];
    const float* as2   = (const float*)d_in[8];
    const float* ad2   = (const float*)d_in[9];
    const float* b2    = (const float*)d_in[10];
    const float* W_act = (const float*)d_in[11];
    const float* b_act = (const float*)d_in[12];
    const float* W_cri = (const float*)d_in[13];
    const float* b_cri = (const float*)d_in[14];
    float* out = (float*)d_out;

    float* p = (float*)d_ws;
    float* h2    = p; p += N * HD;
    float* ssrc1 = p; p += H * N;
    float* sdst1 = p; p += H * N;
    float* ssrc2 = p; p += H * N;
    float* sdst2 = p; p += H * N;
    float* srtv  = p; p += H * N;
    int*   srti  = (int*)p; p += H * N;
    float* TA    = p; p += H * 64 * TS;
    float* TB    = p; p += H * 64 * TS;
    float* SA    = p; p += (size_t)H * (N + 1) * TS;
    float* PB    = p; p += (size_t)H * (N + 1) * TS;
    int*   rpart = (int*)p; p += 16 * H * N;
    int*   cnt1  = (int*)p; p += 64;
    int*   done1 = (int*)p; p += 4;
    int*   cnt2  = (int*)p; p += 64;
    int*   done2 = (int*)p; p += 4;

    hipMemsetAsync(cnt1, 0, 136 * sizeof(int), stream);

    dim3 rgrid(64, 16);

    // layer 1
    k_encproj<<<N / 8, 256, 0, stream>>>(x, W_enc, b_enc, W1, as1, ad1,
                                         h2, ssrc1, sdst1);
    k_rank_f<<<rgrid, 256, 0, stream>>>(ssrc1, rpart, cnt1, srtv, srti);
    k_scan<<<256, 128, 0, stream>>>(h2, srti, srtv, TA, TB, done1, SA, PB);
    k_targetproj<<<N / 8, 256, 0, stream>>>(sdst1, srtv, SA, PB, b1,
                                            W2, as2, ad2, h2, ssrc2, sdst2);
    // layer 2
    k_rank_f<<<rgrid, 256, 0, stream>>>(ssrc2, rpart, cnt2, srtv, srti);
    k_scan<<<256, 128, 0, stream>>>(h2, srti, srtv, TA, TB, done2, SA, PB);
    k_target2<<<N / 4, 256, 0, stream>>>(sdst2, srtv, SA, PB, b2,
                                         W_act, b_act, W_cri, b_cri, out);
}

// Round 10
// 129.626 us; speedup vs baseline: 3.5393x; 1.8149x over previous
//
#include <hip/hip_runtime.h>

// GAT on fully-connected graph, N=4096, F=D=64, H=4, OUT=2.
// 7 fence-free dispatches: encproj | rankF | scanF | targetproj | rankF |
// scanF | target2. Intra-kernel cross-block data goes through IF$-coherent
// relaxed agent-scope atomics (no L2 fences, no acquire-poll invalidate
// storms); inter-kernel data uses normal stores (kernel-boundary flush).
// e[t,s,h]=lrelu(dst_t+src_s) factors per branch around -dst: sorted-source
// suffix/prefix weighted tables + rank search per target.

#define N 4096
#define D 64
#define H 4
#define HD 256
#define TS 66

#define AS(p, v) __hip_atomic_store((p), (v), __ATOMIC_RELAXED, __HIP_MEMORY_SCOPE_AGENT)
#define AL(p)    __hip_atomic_load((p), __ATOMIC_RELAXED, __HIP_MEMORY_SCOPE_AGENT)

__device__ __forceinline__ void fma4(float4& a, float s, const float4& b) {
  a.x = fmaf(s, b.x, a.x); a.y = fmaf(s, b.y, a.y);
  a.z = fmaf(s, b.z, a.z); a.w = fmaf(s, b.w, a.w);
}

// ---- proj: 8 rows from LDS xs, W from global; writes h2, ssrc, sdst ----
__device__ __forceinline__ void proj_dev(const float (*xs)[64], int r0,
    const float* __restrict__ W, const float* __restrict__ asrc,
    const float* __restrict__ adst, float* __restrict__ h2,
    float* __restrict__ ssrc, float* __restrict__ sdst) {
  int tid = threadIdx.x;
  int lane6 = tid & 63;
  int c0 = lane6 * 4;
  int hh = lane6 >> 4;
  int rbase = (tid >> 6) * 2;
  float4 acc0 = make_float4(0.f, 0.f, 0.f, 0.f);
  float4 acc1 = make_float4(0.f, 0.f, 0.f, 0.f);
#pragma unroll
  for (int kq = 0; kq < 16; ++kq) {
    const float* Wk = W + kq * 4 * 256 + c0;
    float4 w0 = *(const float4*)(Wk);
    float4 w1 = *(const float4*)(Wk + 256);
    float4 w2 = *(const float4*)(Wk + 512);
    float4 w3 = *(const float4*)(Wk + 768);
    float4 x0 = *(const float4*)(&xs[rbase][kq * 4]);
    float4 x1 = *(const float4*)(&xs[rbase + 1][kq * 4]);
    fma4(acc0, x0.x, w0); fma4(acc0, x0.y, w1); fma4(acc0, x0.z, w2); fma4(acc0, x0.w, w3);
    fma4(acc1, x1.x, w0); fma4(acc1, x1.y, w1); fma4(acc1, x1.z, w2); fma4(acc1, x1.w, w3);
  }
  float4 av = *(const float4*)(asrc + c0);
  float4 bv = *(const float4*)(adst + c0);
#pragma unroll
  for (int r = 0; r < 2; ++r) {
    float4 a = (r == 0) ? acc0 : acc1;
    int row = r0 + rbase + r;
    *(float4*)(h2 + row * 256 + c0) = a;
    float ps = a.x * av.x + a.y * av.y + a.z * av.z + a.w * av.w;
    float pd = a.x * bv.x + a.y * bv.y + a.z * bv.z + a.w * bv.w;
#pragma unroll
    for (int off = 8; off > 0; off >>= 1) {
      ps += __shfl_down(ps, off);
      pd += __shfl_down(pd, off);
    }
    if ((lane6 & 15) == 0) {
      ssrc[hh * N + row] = ps;
      sdst[hh * N + row] = pd;
    }
  }
}

// ---- layer1: encoder fused with proj; block 0 zeroes sync counters ----
__global__ __launch_bounds__(256) void k_encproj(const float* __restrict__ x,
    const float* __restrict__ Wenc, const float* __restrict__ benc,
    const float* __restrict__ W, const float* __restrict__ asrc,
    const float* __restrict__ adst, float* __restrict__ h2,
    float* __restrict__ ssrc, float* __restrict__ sdst,
    int* __restrict__ sync) {
  __shared__ float xs[8][64];
  int tid = threadIdx.x;
  int r0 = blockIdx.x * 8;
  if (blockIdx.x == 0 && tid < 136) sync[tid] = 0;
  {
    int row = tid >> 5, c = (tid & 31) * 2;
    const float* xr = x + (r0 + row) * 64;
    float a0 = benc[c], a1 = benc[c + 1];
#pragma unroll
    for (int k = 0; k < 64; ++k) {
      float xv = xr[k];
      float2 w = *(const float2*)(Wenc + k * 64 + c);
      a0 = fmaf(xv, w.x, a0);
      a1 = fmaf(xv, w.y, a1);
    }
    xs[row][c] = fmaxf(a0, 0.f);
    xs[row][c + 1] = fmaxf(a1, 0.f);
  }
  __syncthreads();
  proj_dev(xs, r0, W, asrc, adst, h2, ssrc, sdst);
}

// ---- rank fused: partial counts via IF$ atomics; last block reduces ----
// grid (64, 16): x = h*16+ig, y = c. No fences anywhere.
__global__ __launch_bounds__(256) void k_rank_f(const float* __restrict__ ssrc,
    int* __restrict__ rpart, int* __restrict__ cnt,
    float* __restrict__ srtv, int* __restrict__ srti) {
  __shared__ __align__(16) float vs[256];
  __shared__ int lastflag;
  int h = blockIdx.x >> 4, ig = blockIdx.x & 15, c = blockIdx.y;
  int tid = threadIdx.x;
  vs[tid] = ssrc[h * N + c * 256 + tid];
  __syncthreads();
  int i = ig * 256 + tid;
  float vi = ssrc[h * N + i];
  int jbase = c * 256;
  int rank = 0;
  const float4* vs4 = (const float4*)vs;
#pragma unroll 4
  for (int j4 = 0; j4 < 64; ++j4) {
    float4 q = vs4[j4];
    int jb = jbase + (j4 << 2);
    rank += (q.x < vi || (q.x == vi && jb < i));
    rank += (q.y < vi || (q.y == vi && jb + 1 < i));
    rank += (q.z < vi || (q.z == vi && jb + 2 < i));
    rank += (q.w < vi || (q.w == vi && jb + 3 < i));
  }
  AS(&rpart[(c * H + h) * N + i], rank);               // IF$-coherent store
  asm volatile("s_waitcnt vmcnt(0)" ::: "memory");     // my store is globally visible
  __syncthreads();                                     // whole block's stores visible
  if (tid == 0) {
    int prev = __hip_atomic_fetch_add(&cnt[h * 16 + ig], 1,
                 __ATOMIC_RELAXED, __HIP_MEMORY_SCOPE_AGENT);
    lastflag = (prev == 15);
  }
  __syncthreads();
  if (lastflag) {
    int rk = 0;
#pragma unroll
    for (int cc = 0; cc < 16; ++cc) rk += AL(&rpart[(cc * H + h) * N + i]);
    srtv[h * N + rk] = vi;   // normal stores: read by NEXT kernel (boundary flush)
    srti[h * N + rk] = i;
  }
}

// ---- scan: s1 totals (IF$ atomics) + relaxed spin + s3 tables ----
// grid 256 (h*64+c), block 128: 1 block/CU -> co-residency guaranteed.
__global__ __launch_bounds__(128) void k_scan(const float* __restrict__ h2,
    const int* __restrict__ srti, const float* __restrict__ srtv,
    float* __restrict__ TA, float* __restrict__ TB, int* __restrict__ done,
    float* __restrict__ SA, float* __restrict__ PB) {
  __shared__ int pj[64];
  __shared__ float wa[64], wb[64];
  int h = blockIdx.x >> 6, c = blockIdx.x & 63, col = threadIdx.x;
  int j0 = c * 64;
  float m1 = srtv[h * N + N - 1];
  if (col < 64) {
    int j = j0 + col;
    pj[col] = srti[h * N + j];
    float sv = srtv[h * N + j];
    wa[col] = expf(sv - m1);
    wb[col] = expf(0.2f * (sv - m1));
  }
  __syncthreads();
  float v[64];
  if (col < 65) {
    float tA = 0.f, tB = 0.f;
#pragma unroll
    for (int j = 0; j < 64; ++j) {
      v[j] = (col < 64) ? h2[pj[j] * HD + h * 64 + col] : 1.0f;
      tA = fmaf(wa[j], v[j], tA);
      tB = fmaf(wb[j], v[j], tB);
    }
    AS(&TA[(h * 64 + c) * TS + col], tA);
    AS(&TB[(h * 64 + c) * TS + col], tB);
  }
  asm volatile("s_waitcnt vmcnt(0)" ::: "memory");
  __syncthreads();
  if (col == 0) {
    __hip_atomic_fetch_add(&done[h], 1, __ATOMIC_RELAXED, __HIP_MEMORY_SCOPE_AGENT);
    while (AL(&done[h]) < 64) __builtin_amdgcn_s_sleep(2);   // relaxed poll: no inv
  }
  __syncthreads();
  if (col < 65) {
    float offA = 0.f, offB = 0.f;
    for (int cc = c + 1; cc < 64; ++cc) offA += AL(&TA[(h * 64 + cc) * TS + col]);
    for (int cc = 0; cc < c; ++cc)      offB += AL(&TB[(h * 64 + cc) * TS + col]);
    float acc = offA;
#pragma unroll
    for (int j = 63; j >= 0; --j) {  // SA[i] = sum_{j>=i} wA_j v_j
      acc = fmaf(wa[j], v[j], acc);
      SA[(size_t)(h * (N + 1) + j0 + j) * TS + col] = acc;
    }
    acc = offB;
#pragma unroll
    for (int j = 0; j < 64; ++j) {   // PB[i] = sum_{j<i} wB_j v_j
      acc = fmaf(wb[j], v[j], acc);
      PB[(size_t)(h * (N + 1) + j0 + j + 1) * TS + col] = acc;
    }
    if (c == 63) SA[(size_t)(h * (N + 1) + N) * TS + col] = 0.f;
    if (c == 0)  PB[(size_t)(h * (N + 1) + 0) * TS + col] = 0.f;
  }
}

// ---- target core: rows t0 + tid>>6 + 4*task ----
template <int MODE>
__device__ __forceinline__ void target_dev(int t0, int tid,
    const float* __restrict__ sdst, const float* __restrict__ srtv,
    const float* __restrict__ SA, const float* __restrict__ PB,
    const float* __restrict__ bias, float (*xsout)[64], const float (*bnd)[64],
    const float* __restrict__ Wact, const float* __restrict__ bact,
    const float* __restrict__ Wcri, const float* __restrict__ bcri,
    float* __restrict__ out, int ntask) {
  int lane = tid & 63;
  for (int task = 0; task < ntask; ++task) {
    int r = task * 4 + (tid >> 6);
    int t = t0 + r;
    float acc = 0.f;
#pragma unroll
    for (int h = 0; h < H; ++h) {
      const float* sv = srtv + h * N;
      float dst = sdst[h * N + t];
      float thr = -dst;
      float m1 = sv[N - 1];
      unsigned long long b1m = __ballot(bnd[h][lane] <= thr);
      int c1 = __popcll(b1m);
      int seg = c1 > 0 ? c1 - 1 : 0;
      unsigned long long b2m = __ballot(sv[seg * 64 + lane] <= thr);
      int k = seg * 64 + __popcll(b2m);
      float u = dst + m1;
      float g = fmaxf(u, 0.2f * u);
      float wAt = expf(u - g);
      float wBt = expf(0.2f * u - g);
      const float* sa = SA + (size_t)(h * (N + 1) + k) * TS;
      const float* pb = PB + (size_t)(h * (N + 1) + k) * TS;
      float num = wAt * sa[lane] + wBt * pb[lane];
      float den = wAt * sa[64] + wBt * pb[64];
      acc += num / den;
    }
    float hv = fmaxf(acc * 0.25f + bias[lane], 0.f);
    if constexpr (MODE == 0) {
      xsout[r][lane] = hv;
    } else {
      float p0 = hv * Wact[lane * 2 + 0];
      float p1 = hv * Wact[lane * 2 + 1];
      float p2 = hv * Wcri[lane];
#pragma unroll
      for (int off = 32; off > 0; off >>= 1) {
        p0 += __shfl_down(p0, off);
        p1 += __shfl_down(p1, off);
        p2 += __shfl_down(p2, off);
      }
      if (lane == 0) {
        float l0 = fminf(fmaxf(p0 + bact[0], -5.f), 5.f);
        float l1 = fminf(fmaxf(p1 + bact[1], -5.f), 5.f);
        out[t * 2 + 0] = l0;
        out[t * 2 + 1] = fabsf(l1);
        out[2 * N + t] = p2 + bcri[0];
      }
    }
  }
}

// ---- target1 (8 rows -> LDS) fused with proj2 ----
__global__ __launch_bounds__(256) void k_targetproj(
    const float* __restrict__ sdst, const float* __restrict__ srtv,
    const float* __restrict__ SA, const float* __restrict__ PB,
    const float* __restrict__ bias,
    const float* __restrict__ W, const float* __restrict__ asrc,
    const float* __restrict__ adst, float* __restrict__ h2,
    float* __restrict__ ssrc2, float* __restrict__ sdst2) {
  __shared__ float xs[8][64];
  __shared__ float bnd[4][64];
  int tid = threadIdx.x;
  int r0 = blockIdx.x * 8;
  { int hh = tid >> 6, l = tid & 63; bnd[hh][l] = srtv[hh * N + l * 64]; }
  __syncthreads();
  target_dev<0>(r0, tid, sdst, srtv, SA, PB, bias, xs, bnd,
                nullptr, nullptr, nullptr, nullptr, nullptr, 2);
  __syncthreads();
  proj_dev(xs, r0, W, asrc, adst, h2, ssrc2, sdst2);
}

// ---- target2 + heads ----
__global__ __launch_bounds__(256) void k_target2(
    const float* __restrict__ sdst, const float* __restrict__ srtv,
    const float* __restrict__ SA, const float* __restrict__ PB,
    const float* __restrict__ bias,
    const float* __restrict__ Wact, const float* __restrict__ bact,
    const float* __restrict__ Wcri, const float* __restrict__ bcri,
    float* __restrict__ out) {
  __shared__ float bnd[4][64];
  int tid = threadIdx.x;
  { int hh = tid >> 6, l = tid & 63; bnd[hh][l] = srtv[hh * N + l * 64]; }
  __syncthreads();
  target_dev<1>(blockIdx.x * 4, tid, sdst, srtv, SA, PB, bias, nullptr, bnd,
                Wact, bact, Wcri, bcri, out, 1);
}

extern "C" void kernel_launch(void* const* d_in, const int* in_sizes, int n_in,
                              void* d_out, int out_size, void* d_ws, size_t ws_size,
                              hipStream_t stream) {
    (void)in_sizes; (void)n_in; (void)out_size; (void)ws_size;
    const float* x     = (const float*)d_in[0];
    const float* W_enc = (const float*)d_in[1];
    const float* b_enc = (const float*)d_in[2];
    const float* W1    = (const float*)d_in[3];
    const float* as1   = (const float*)d_in[4];
    const float* ad1   = (const float*)d_in[5];
    const float* b1    = (const float*)d_in[6];
    const float* W2    = (const float*)d_in[7];
    const float* as2   = (const float*)d_in[8];
    const float* ad2   = (const float*)d_in[9];
    const float* b2    = (const float*)d_in[10];
    const float* W_act = (const float*)d_in[11];
    const float* b_act = (const float*)d_in[12];
    const float* W_cri = (const float*)d_in[13];
    const float* b_cri = (const float*)d_in[14];
    float* out = (float*)d_out;

    float* p = (float*)d_ws;
    float* h2    = p; p += N * HD;
    float* ssrc1 = p; p += H * N;
    float* sdst1 = p; p += H * N;
    float* ssrc2 = p; p += H * N;
    float* sdst2 = p; p += H * N;
    float* srtv  = p; p += H * N;
    int*   srti  = (int*)p; p += H * N;
    float* TA    = p; p += H * 64 * TS;
    float* TB    = p; p += H * 64 * TS;
    float* SA    = p; p += (size_t)H * (N + 1) * TS;
    float* PB    = p; p += (size_t)H * (N + 1) * TS;
    int*   rpart = (int*)p; p += 16 * H * N;
    int*   sync  = (int*)p; p += 256;   // [0:64) cnt1, [64:68) done1, [68:132) cnt2, [132:136) done2

    int* cnt1  = sync;
    int* done1 = sync + 64;
    int* cnt2  = sync + 68;
    int* done2 = sync + 132;

    dim3 rgrid(64, 16);

    // layer 1
    k_encproj<<<N / 8, 256, 0, stream>>>(x, W_enc, b_enc, W1, as1, ad1,
                                         h2, ssrc1, sdst1, sync);
    k_rank_f<<<rgrid, 256, 0, stream>>>(ssrc1, rpart, cnt1, srtv, srti);
    k_scan<<<256, 128, 0, stream>>>(h2, srti, srtv, TA, TB, done1, SA, PB);
    k_targetproj<<<N / 8, 256, 0, stream>>>(sdst1, srtv, SA, PB, b1,
                                            W2, as2, ad2, h2, ssrc2, sdst2);
    // layer 2
    k_rank_f<<<rgrid, 256, 0, stream>>>(ssrc2, rpart, cnt2, srtv, srti);
    k_scan<<<256, 128, 0, stream>>>(h2, srti, srtv, TA, TB, done2, SA, PB);
    k_target2<<<N / 4, 256, 0, stream>>>(sdst2, srtv, SA, PB, b2,
                                         W_act, b_act, W_cri, b_cri, out);
}

// Round 11
// 126.115 us; speedup vs baseline: 3.6378x; 1.0278x over previous
//
#include <hip/hip_runtime.h>

// GAT on fully-connected graph, N=4096, F=D=64, H=4, OUT=2.
// 7 fence-free dispatches: encproj | rankF | scanF | targetproj | rankF |
// scanF | target2. Intra-kernel cross-block data via IF$-coherent relaxed
// agent-scope atomics; inter-kernel data via normal stores (boundary flush).
// e[t,s,h]=lrelu(dst_t+src_s) factors per branch around -dst: sorted-source
// suffix/prefix weighted tables + rank search per target.

#define N 4096
#define D 64
#define H 4
#define HD 256
#define TS 66

#define AS(p, v) __hip_atomic_store((p), (v), __ATOMIC_RELAXED, __HIP_MEMORY_SCOPE_AGENT)
#define AL(p)    __hip_atomic_load((p), __ATOMIC_RELAXED, __HIP_MEMORY_SCOPE_AGENT)

__device__ __forceinline__ void fma4(float4& a, float s, const float4& b) {
  a.x = fmaf(s, b.x, a.x); a.y = fmaf(s, b.y, a.y);
  a.z = fmaf(s, b.z, a.z); a.w = fmaf(s, b.w, a.w);
}

// ---- proj: 8 rows from LDS xs, W from global; writes h2, ssrc, sdst ----
__device__ __forceinline__ void proj_dev(const float (*xs)[64], int r0,
    const float* __restrict__ W, const float* __restrict__ asrc,
    const float* __restrict__ adst, float* __restrict__ h2,
    float* __restrict__ ssrc, float* __restrict__ sdst) {
  int tid = threadIdx.x;
  int lane6 = tid & 63;
  int c0 = lane6 * 4;
  int hh = lane6 >> 4;
  int rbase = (tid >> 6) * 2;
  float4 acc0 = make_float4(0.f, 0.f, 0.f, 0.f);
  float4 acc1 = make_float4(0.f, 0.f, 0.f, 0.f);
#pragma unroll
  for (int kq = 0; kq < 16; ++kq) {
    const float* Wk = W + kq * 4 * 256 + c0;
    float4 w0 = *(const float4*)(Wk);
    float4 w1 = *(const float4*)(Wk + 256);
    float4 w2 = *(const float4*)(Wk + 512);
    float4 w3 = *(const float4*)(Wk + 768);
    float4 x0 = *(const float4*)(&xs[rbase][kq * 4]);
    float4 x1 = *(const float4*)(&xs[rbase + 1][kq * 4]);
    fma4(acc0, x0.x, w0); fma4(acc0, x0.y, w1); fma4(acc0, x0.z, w2); fma4(acc0, x0.w, w3);
    fma4(acc1, x1.x, w0); fma4(acc1, x1.y, w1); fma4(acc1, x1.z, w2); fma4(acc1, x1.w, w3);
  }
  float4 av = *(const float4*)(asrc + c0);
  float4 bv = *(const float4*)(adst + c0);
#pragma unroll
  for (int r = 0; r < 2; ++r) {
    float4 a = (r == 0) ? acc0 : acc1;
    int row = r0 + rbase + r;
    *(float4*)(h2 + row * 256 + c0) = a;
    float ps = a.x * av.x + a.y * av.y + a.z * av.z + a.w * av.w;
    float pd = a.x * bv.x + a.y * bv.y + a.z * bv.z + a.w * bv.w;
#pragma unroll
    for (int off = 8; off > 0; off >>= 1) {
      ps += __shfl_down(ps, off);
      pd += __shfl_down(pd, off);
    }
    if ((lane6 & 15) == 0) {
      ssrc[hh * N + row] = ps;
      sdst[hh * N + row] = pd;
    }
  }
}

// ---- layer1: encoder fused with proj; block 0 zeroes sync counters ----
__global__ __launch_bounds__(256) void k_encproj(const float* __restrict__ x,
    const float* __restrict__ Wenc, const float* __restrict__ benc,
    const float* __restrict__ W, const float* __restrict__ asrc,
    const float* __restrict__ adst, float* __restrict__ h2,
    float* __restrict__ ssrc, float* __restrict__ sdst,
    int* __restrict__ sync) {
  __shared__ float xs[8][64];
  int tid = threadIdx.x;
  int r0 = blockIdx.x * 8;
  if (blockIdx.x == 0 && tid < 136) sync[tid] = 0;
  {
    int row = tid >> 5, c = (tid & 31) * 2;
    const float* xr = x + (r0 + row) * 64;
    float a0 = benc[c], a1 = benc[c + 1];
#pragma unroll
    for (int k = 0; k < 64; ++k) {
      float xv = xr[k];
      float2 w = *(const float2*)(Wenc + k * 64 + c);
      a0 = fmaf(xv, w.x, a0);
      a1 = fmaf(xv, w.y, a1);
    }
    xs[row][c] = fmaxf(a0, 0.f);
    xs[row][c + 1] = fmaxf(a1, 0.f);
  }
  __syncthreads();
  proj_dev(xs, r0, W, asrc, adst, h2, ssrc, sdst);
}

// ---- rank fused: partial counts via IF$ atomics; last block reduces ----
// grid (64, 16): x = h*16+ig, y = c. No fences anywhere.
__global__ __launch_bounds__(256) void k_rank_f(const float* __restrict__ ssrc,
    int* __restrict__ rpart, int* __restrict__ cnt,
    float* __restrict__ srtv, int* __restrict__ srti) {
  __shared__ __align__(16) float vs[256];
  __shared__ int lastflag;
  int h = blockIdx.x >> 4, ig = blockIdx.x & 15, c = blockIdx.y;
  int tid = threadIdx.x;
  vs[tid] = ssrc[h * N + c * 256 + tid];
  __syncthreads();
  int i = ig * 256 + tid;
  float vi = ssrc[h * N + i];
  int jbase = c * 256;
  int rank = 0;
  const float4* vs4 = (const float4*)vs;
#pragma unroll 4
  for (int j4 = 0; j4 < 64; ++j4) {
    float4 q = vs4[j4];
    int jb = jbase + (j4 << 2);
    rank += (q.x < vi || (q.x == vi && jb < i));
    rank += (q.y < vi || (q.y == vi && jb + 1 < i));
    rank += (q.z < vi || (q.z == vi && jb + 2 < i));
    rank += (q.w < vi || (q.w == vi && jb + 3 < i));
  }
  AS(&rpart[(c * H + h) * N + i], rank);               // IF$-coherent store
  asm volatile("s_waitcnt vmcnt(0)" ::: "memory");     // my store globally visible
  __syncthreads();                                     // whole block's stores visible
  if (tid == 0) {
    int prev = __hip_atomic_fetch_add(&cnt[h * 16 + ig], 1,
                 __ATOMIC_RELAXED, __HIP_MEMORY_SCOPE_AGENT);
    lastflag = (prev == 15);
  }
  __syncthreads();
  if (lastflag) {
    int rk = 0;
#pragma unroll
    for (int cc = 0; cc < 16; ++cc) rk += AL(&rpart[(cc * H + h) * N + i]);
    srtv[h * N + rk] = vi;   // normal stores: read by NEXT kernel
    srti[h * N + rk] = i;
  }
}

// ---- scan: 4-wave blocks; LDS tile gather; hierarchical prefix/suffix ----
// grid 256 (h*64+c), block 256: co-residency guaranteed (1 block/CU).
__global__ __launch_bounds__(256) void k_scan(const float* __restrict__ h2,
    const int* __restrict__ srti, const float* __restrict__ srtv,
    float* __restrict__ TA, float* __restrict__ TB, int* __restrict__ done,
    float* __restrict__ SA, float* __restrict__ PB) {
  __shared__ int pj[64];
  __shared__ float wa[64], wb[64];
  __shared__ float vt[64][66];                // gathered 64x64 tile
  __shared__ float segA[4][66], segB[4][66];  // per-wave segment sums (col64 = wsum)
  __shared__ float chA[66], chB[66];          // chunk-level offsets
  int h = blockIdx.x >> 6, c = blockIdx.x & 63;
  int tid = threadIdx.x, w = tid >> 6, lane = tid & 63;
  int j0 = c * 64;
  float m1 = srtv[h * N + N - 1];
  if (tid < 64) {
    int j = j0 + tid;
    pj[tid] = srti[h * N + j];
    float sv = srtv[h * N + j];
    wa[tid] = expf(sv - m1);
    wb[tid] = expf(0.2f * (sv - m1));
  }
  __syncthreads();
  // cooperative gather: 4 rows in flight, 16 iterations
#pragma unroll
  for (int jj = 0; jj < 16; ++jj) {
    int j = jj * 4 + w;
    vt[j][lane] = h2[pj[j] * HD + h * 64 + lane];
  }
  __syncthreads();
  // per-wave segment sums over rows [w*16, w*16+16)
  {
    float sA = 0.f, sB = 0.f, swA = 0.f, swB = 0.f;
#pragma unroll
    for (int jj = 0; jj < 16; ++jj) {
      int j = w * 16 + jj;
      float v = vt[j][lane];
      float a = wa[j], b = wb[j];
      sA = fmaf(a, v, sA);
      sB = fmaf(b, v, sB);
      swA += a; swB += b;
    }
    segA[w][lane] = sA; segB[w][lane] = sB;
    if (lane == 0) { segA[w][64] = swA; segB[w][64] = swB; }
  }
  __syncthreads();
  // publish chunk totals (IF$-coherent)
  if (tid < 65) {
    float tA = segA[0][tid] + segA[1][tid] + segA[2][tid] + segA[3][tid];
    float tB = segB[0][tid] + segB[1][tid] + segB[2][tid] + segB[3][tid];
    AS(&TA[(h * 64 + c) * TS + tid], tA);
    AS(&TB[(h * 64 + c) * TS + tid], tB);
  }
  asm volatile("s_waitcnt vmcnt(0)" ::: "memory");
  __syncthreads();
  if (tid == 0) {
    __hip_atomic_fetch_add(&done[h], 1, __ATOMIC_RELAXED, __HIP_MEMORY_SCOPE_AGENT);
    while (AL(&done[h]) < 64) __builtin_amdgcn_s_sleep(2);   // relaxed poll
  }
  __syncthreads();
  // chunk-level offsets from other chunks' totals
  if (tid < 65) {
    float oA = 0.f, oB = 0.f;
    for (int cc = c + 1; cc < 64; ++cc) oA += AL(&TA[(h * 64 + cc) * TS + tid]);
    for (int cc = 0; cc < c; ++cc)      oB += AL(&TB[(h * 64 + cc) * TS + tid]);
    chA[tid] = oA; chB[tid] = oB;
  }
  __syncthreads();
  // wave w builds rows [w*16, w*16+16): SA suffix (descending), PB prefix (ascending)
  size_t base = (size_t)h * (N + 1);
  {
    float aboveA = 0.f, aboveW = 0.f;
    for (int w2 = w + 1; w2 < 4; ++w2) { aboveA += segA[w2][lane]; aboveW += segA[w2][64]; }
    float accA = chA[lane] + aboveA;
    float waccA = chA[64] + aboveW;
#pragma unroll
    for (int jj = 15; jj >= 0; --jj) {
      int j = w * 16 + jj;
      accA = fmaf(wa[j], vt[j][lane], accA);
      waccA += wa[j];
      float* row = SA + (base + j0 + j) * TS;
      row[lane] = accA;
      if (lane == 0) row[64] = waccA;
    }
  }
  {
    float belowB = 0.f, belowW = 0.f;
    for (int w2 = 0; w2 < w; ++w2) { belowB += segB[w2][lane]; belowW += segB[w2][64]; }
    float accB = chB[lane] + belowB;
    float waccB = chB[64] + belowW;
#pragma unroll
    for (int jj = 0; jj < 16; ++jj) {
      int j = w * 16 + jj;
      accB = fmaf(wb[j], vt[j][lane], accB);
      waccB += wb[j];
      float* row = PB + (base + j0 + j + 1) * TS;
      row[lane] = accB;
      if (lane == 0) row[64] = waccB;
    }
  }
  if (c == 63 && tid < 65) SA[(base + N) * TS + tid] = 0.f;
  if (c == 0 && tid < 65)  PB[(base + 0) * TS + tid] = 0.f;
}

// ---- target core: rows t0 + tid>>6 + 4*task ----
template <int MODE>
__device__ __forceinline__ void target_dev(int t0, int tid,
    const float* __restrict__ sdst, const float* __restrict__ srtv,
    const float* __restrict__ SA, const float* __restrict__ PB,
    const float* __restrict__ bias, float (*xsout)[64], const float (*bnd)[64],
    const float* __restrict__ Wact, const float* __restrict__ bact,
    const float* __restrict__ Wcri, const float* __restrict__ bcri,
    float* __restrict__ out, int ntask) {
  int lane = tid & 63;
  for (int task = 0; task < ntask; ++task) {
    int r = task * 4 + (tid >> 6);
    int t = t0 + r;
    float acc = 0.f;
#pragma unroll
    for (int h = 0; h < H; ++h) {
      const float* sv = srtv + h * N;
      float dst = sdst[h * N + t];
      float thr = -dst;
      float m1 = sv[N - 1];
      unsigned long long b1m = __ballot(bnd[h][lane] <= thr);
      int c1 = __popcll(b1m);
      int seg = c1 > 0 ? c1 - 1 : 0;
      unsigned long long b2m = __ballot(sv[seg * 64 + lane] <= thr);
      int k = seg * 64 + __popcll(b2m);
      float u = dst + m1;
      float g = fmaxf(u, 0.2f * u);
      float wAt = expf(u - g);
      float wBt = expf(0.2f * u - g);
      const float* sa = SA + (size_t)(h * (N + 1) + k) * TS;
      const float* pb = PB + (size_t)(h * (N + 1) + k) * TS;
      float num = wAt * sa[lane] + wBt * pb[lane];
      float den = wAt * sa[64] + wBt * pb[64];
      acc += num / den;
    }
    float hv = fmaxf(acc * 0.25f + bias[lane], 0.f);
    if constexpr (MODE == 0) {
      xsout[r][lane] = hv;
    } else {
      float p0 = hv * Wact[lane * 2 + 0];
      float p1 = hv * Wact[lane * 2 + 1];
      float p2 = hv * Wcri[lane];
#pragma unroll
      for (int off = 32; off > 0; off >>= 1) {
        p0 += __shfl_down(p0, off);
        p1 += __shfl_down(p1, off);
        p2 += __shfl_down(p2, off);
      }
      if (lane == 0) {
        float l0 = fminf(fmaxf(p0 + bact[0], -5.f), 5.f);
        float l1 = fminf(fmaxf(p1 + bact[1], -5.f), 5.f);
        out[t * 2 + 0] = l0;
        out[t * 2 + 1] = fabsf(l1);
        out[2 * N + t] = p2 + bcri[0];
      }
    }
  }
}

// ---- target1 (8 rows -> LDS) fused with proj2 ----
__global__ __launch_bounds__(256) void k_targetproj(
    const float* __restrict__ sdst, const float* __restrict__ srtv,
    const float* __restrict__ SA, const float* __restrict__ PB,
    const float* __restrict__ bias,
    const float* __restrict__ W, const float* __restrict__ asrc,
    const float* __restrict__ adst, float* __restrict__ h2,
    float* __restrict__ ssrc2, float* __restrict__ sdst2) {
  __shared__ float xs[8][64];
  __shared__ float bnd[4][64];
  int tid = threadIdx.x;
  int r0 = blockIdx.x * 8;
  { int hh = tid >> 6, l = tid & 63; bnd[hh][l] = srtv[hh * N + l * 64]; }
  __syncthreads();
  target_dev<0>(r0, tid, sdst, srtv, SA, PB, bias, xs, bnd,
                nullptr, nullptr, nullptr, nullptr, nullptr, 2);
  __syncthreads();
  proj_dev(xs, r0, W, asrc, adst, h2, ssrc2, sdst2);
}

// ---- target2 + heads ----
__global__ __launch_bounds__(256) void k_target2(
    const float* __restrict__ sdst, const float* __restrict__ srtv,
    const float* __restrict__ SA, const float* __restrict__ PB,
    const float* __restrict__ bias,
    const float* __restrict__ Wact, const float* __restrict__ bact,
    const float* __restrict__ Wcri, const float* __restrict__ bcri,
    float* __restrict__ out) {
  __shared__ float bnd[4][64];
  int tid = threadIdx.x;
  { int hh = tid >> 6, l = tid & 63; bnd[hh][l] = srtv[hh * N + l * 64]; }
  __syncthreads();
  target_dev<1>(blockIdx.x * 4, tid, sdst, srtv, SA, PB, bias, nullptr, bnd,
                Wact, bact, Wcri, bcri, out, 1);
}

extern "C" void kernel_launch(void* const* d_in, const int* in_sizes, int n_in,
                              void* d_out, int out_size, void* d_ws, size_t ws_size,
                              hipStream_t stream) {
    (void)in_sizes; (void)n_in; (void)out_size; (void)ws_size;
    const float* x     = (const float*)d_in[0];
    const float* W_enc = (const float*)d_in[1];
    const float* b_enc = (const float*)d_in[2];
    const float* W1    = (const float*)d_in[3];
    const float* as1   = (const float*)d_in[4];
    const float* ad1   = (const float*)d_in[5];
    const float* b1    = (const float*)d_in[6];
    const float* W2    = (const float*)d_in[7];
    const float* as2   = (const float*)d_in[8];
    const float* ad2   = (const float*)d_in[9];
    const float* b2    = (const float*)d_in[10];
    const float* W_act = (const float*)d_in[11];
    const float* b_act = (const float*)d_in[12];
    const float* W_cri = (const float*)d_in[13];
    const float* b_cri = (const float*)d_in[14];
    float* out = (float*)d_out;

    float* p = (float*)d_ws;
    float* h2    = p; p += N * HD;
    float* ssrc1 = p; p += H * N;
    float* sdst1 = p; p += H * N;
    float* ssrc2 = p; p += H * N;
    float* sdst2 = p; p += H * N;
    float* srtv  = p; p += H * N;
    int*   srti  = (int*)p; p += H * N;
    float* TA    = p; p += H * 64 * TS;
    float* TB    = p; p += H * 64 * TS;
    float* SA    = p; p += (size_t)H * (N + 1) * TS;
    float* PB    = p; p += (size_t)H * (N + 1) * TS;
    int*   rpart = (int*)p; p += 16 * H * N;
    int*   sync  = (int*)p; p += 256;

    int* cnt1  = sync;
    int* done1 = sync + 64;
    int* cnt2  = sync + 68;
    int* done2 = sync + 132;

    dim3 rgrid(64, 16);

    // layer 1
    k_encproj<<<N / 8, 256, 0, stream>>>(x, W_enc, b_enc, W1, as1, ad1,
                                         h2, ssrc1, sdst1, sync);
    k_rank_f<<<rgrid, 256, 0, stream>>>(ssrc1, rpart, cnt1, srtv, srti);
    k_scan<<<256, 256, 0, stream>>>(h2, srti, srtv, TA, TB, done1, SA, PB);
    k_targetproj<<<N / 8, 256, 0, stream>>>(sdst1, srtv, SA, PB, b1,
                                            W2, as2, ad2, h2, ssrc2, sdst2);
    // layer 2
    k_rank_f<<<rgrid, 256, 0, stream>>>(ssrc2, rpart, cnt2, srtv, srti);
    k_scan<<<256, 256, 0, stream>>>(h2, srti, srtv, TA, TB, done2, SA, PB);
    k_target2<<<N / 4, 256, 0, stream>>>(sdst2, srtv, SA, PB, b2,
                                         W_act, b_act, W_cri, b_cri, out);
}